// Round 1
// 222.272 us; speedup vs baseline: 1.1215x; 1.1215x over previous
//
#include <hip/hip_runtime.h>
#include <hip/hip_bf16.h>

typedef __bf16 bf16x8 __attribute__((ext_vector_type(8)));
typedef float f32x4 __attribute__((ext_vector_type(4)));

#define LAT 512

__device__ __forceinline__ void async_load16(const void* g, void* l) {
  __builtin_amdgcn_global_load_lds(
      (const __attribute__((address_space(1))) unsigned int*)g,
      (__attribute__((address_space(3))) unsigned int*)l, 16, 0, 0);
}

// ---------------- kernel 1: style affine  s[b][cin] = style[b]@style_w[:,cin] + style_b[cin]
__global__ void style_kernel(const float* __restrict__ style,
                             const float* __restrict__ style_w,
                             const float* __restrict__ style_b,
                             float* __restrict__ smod) {
  int b = blockIdx.x, cin = threadIdx.x;
  float acc = style_b[cin];
  const float* st = style + b * LAT;
  for (int l = 0; l < LAT; ++l)
    acc = fmaf(st[l], style_w[l * 256 + cin], acc);
  smod[b * 256 + cin] = acc;
}

// ---------------- kernel 2: modulate + demodulate -> bf16 wmod[b][tap][cout][cin]
__global__ void modw_kernel(const float* __restrict__ weight,
                            const float* __restrict__ smod,
                            __hip_bfloat16* __restrict__ wmod) {
  int cout = blockIdx.x, b = blockIdx.y;
  int cin = threadIdx.x;
  float s = smod[b * 256 + cin];
  const float* wp = weight + ((size_t)cout * 256 + cin) * 9;
  float w[9];
  float ss = 0.f;
#pragma unroll
  for (int j = 0; j < 9; ++j) { w[j] = wp[j]; ss = fmaf(w[j], w[j], ss); }
  ss *= s * s;
#pragma unroll
  for (int off = 32; off > 0; off >>= 1) ss += __shfl_down(ss, off, 64);
  __shared__ float red[4];
  __shared__ float dsh;
  int lane = threadIdx.x & 63, wv = threadIdx.x >> 6;
  if (lane == 0) red[wv] = ss;
  __syncthreads();
  if (threadIdx.x == 0) dsh = rsqrtf(red[0] + red[1] + red[2] + red[3] + 1e-8f);
  __syncthreads();
  float d = dsh * s;
  size_t obase = ((size_t)(b * 9) * 256 + cout) * 256 + cin;
#pragma unroll
  for (int j = 0; j < 9; ++j)
    wmod[obase + (size_t)j * 65536] = __float2bfloat16(w[j] * d);
}

// ---------------- kernel 3: zero the pad border of x_t[b][66][66][256]
__global__ void border_kernel(__hip_bfloat16* __restrict__ xt) {
  int bp = blockIdx.x;  // 0..259
  int b = blockIdx.y;
  int h, w;
  if (bp < 66)       { h = 0;        w = bp; }
  else if (bp < 132) { h = 65;       w = bp - 66; }
  else if (bp < 196) { h = bp - 131; w = 0; }
  else               { h = bp - 195; w = 65; }
  xt[((size_t)(b * 66 + h) * 66 + w) * 256 + threadIdx.x] = __float2bfloat16(0.f);
}

// ---------------- kernel 4: NCHW fp32 -> padded NHWC bf16
__global__ void transpose_kernel(const float* __restrict__ x,
                                 __hip_bfloat16* __restrict__ xt) {
  __shared__ __hip_bfloat16 tile[64][258];
  int h = blockIdx.x, b = blockIdx.y, t = threadIdx.x;
  int w4 = (t & 15) * 4;
  int csub = t >> 4;  // 0..15
  for (int c0 = 0; c0 < 256; c0 += 16) {
    int cin = c0 + csub;
    const float4 v = *(const float4*)(x + (((size_t)(b * 256 + cin) * 64 + h) << 6) + w4);
    tile[w4 + 0][cin] = __float2bfloat16(v.x);
    tile[w4 + 1][cin] = __float2bfloat16(v.y);
    tile[w4 + 2][cin] = __float2bfloat16(v.z);
    tile[w4 + 3][cin] = __float2bfloat16(v.w);
  }
  __syncthreads();
  int wsub = t >> 7;    // 0..1
  int cpair = t & 127;  // 0..127
  size_t obase = ((size_t)(b * 66 + h + 1) * 66 + 1) * 256;
  for (int w0 = 0; w0 < 64; w0 += 2) {
    int w = w0 + wsub;
    unsigned int v = *(const unsigned int*)&tile[w][cpair * 2];
    *(unsigned int*)((__hip_bfloat16*)xt + obase + (size_t)w * 256 + cpair * 2) = v;
  }
}

// ---------------- kernel 5: implicit-GEMM conv + noise + bias + lrelu*sqrt2
// 2-deep software pipeline: double-buffered 32KB stages, counted vmcnt(8),
// raw s_barrier (no vmcnt(0) drain in steady state).  XCD-chunked block swizzle.
// grid: (32 spatial tiles, 2 cout tiles, 16 batch) -> swizzled, 256 threads
__global__ __launch_bounds__(256, 2)
void conv_kernel(const __hip_bfloat16* __restrict__ wmod,
                 const __hip_bfloat16* __restrict__ xt,
                 const float* __restrict__ noise,
                 const float* __restrict__ bias,
                 const float* __restrict__ nwt,
                 float* __restrict__ out) {
  __shared__ __align__(16) char lds[65536];  // dbuf: [0,32K) and [32K,64K); each: A 16K + B 16K
  const int t = threadIdx.x;

  // ---- XCD-aware bijective swizzle: 1024 blocks, 8 XCDs, 128 blocks/XCD.
  // nid ordering inside an XCD: spatial fastest, then cout-half, then batch ->
  // concurrent ~64 blocks/XCD share one batch's xt (2.2MB) + its wmod (1.2MB) < 4MB L2.
  const int bid = blockIdx.x + (blockIdx.y << 5) + (blockIdx.z << 6);
  const int nid = ((bid & 7) << 7) + (bid >> 3);
  const int bx = nid & 31;                 // spatial tile: rows 2*bx, 2*bx+1
  const int cout0 = ((nid >> 5) & 1) << 7; // 0 or 128
  const int b = nid >> 6;                  // batch

  // staging source offsets (elements). e = i*256+t covers 1024 16B chunks.
  size_t a_off[4], b_off[4];
  const size_t wbase = (size_t)b * 9 * 65536;
#pragma unroll
  for (int i = 0; i < 4; ++i) {
    int e = i * 256 + t;
    int m = e >> 3, c8 = e & 7;
    int gk8 = c8 ^ (m & 7);  // XOR swizzle: permute SOURCE chunk, dest is fixed
    a_off[i] = (size_t)(cout0 + m) * 256 + gk8 * 8;
    int hrow = m >> 6, wcol = m & 63;
    b_off[i] = ((size_t)(b * 66 + bx * 2 + hrow) * 66 + wcol) * 256 + gk8 * 8;
  }

  const int lane = t & 63;
  const int wv = t >> 6;
  const int mw = (wv >> 1) * 64, nwl = (wv & 1) * 64;
  const int col = lane & 15, quad = lane >> 4;

  // fragment LDS byte offsets (swizzled), relative to buffer base
  int aro[4][2], bro[4][2];
#pragma unroll
  for (int i = 0; i < 4; ++i) {
    int m = mw + i * 16 + col;
    int n = nwl + i * 16 + col;
#pragma unroll
    for (int ks = 0; ks < 2; ++ks) {
      int k8 = ks * 4 + quad;
      aro[i][ks] = (m * 8 + (k8 ^ (m & 7))) * 16;
      bro[i][ks] = 16384 + (n * 8 + (k8 ^ (n & 7))) * 16;
    }
  }

  f32x4 acc[4][4];
#pragma unroll
  for (int i = 0; i < 4; ++i)
#pragma unroll
    for (int j = 0; j < 4; ++j)
      acc[i][j] = (f32x4){0.f, 0.f, 0.f, 0.f};

  // stage st (0..35): tap s9 = st>>2, k-chunk kc = st&3. 8 global_load_lds each.
  auto stage_fn = [&](int st, int bo) {
    const int s9 = st >> 2, kc = st & 3;
    const int kh = s9 / 3, kw = s9 - 3 * kh;
    const size_t abase = wbase + ((size_t)s9 << 16) + (kc << 6);
    const size_t bbase = (size_t)((kh * 66 + kw) << 8) + (kc << 6);
#pragma unroll
    for (int i = 0; i < 4; ++i) {
      async_load16(wmod + abase + a_off[i], lds + bo + i * 4096 + t * 16);
      async_load16(xt + bbase + b_off[i], lds + bo + 16384 + i * 4096 + t * 16);
    }
  };

  auto compute_fn = [&](int bo) {
#pragma unroll
    for (int ks = 0; ks < 2; ++ks) {
      bf16x8 af[4], bfr[4];
#pragma unroll
      for (int i = 0; i < 4; ++i) af[i] = *(const bf16x8*)(lds + bo + aro[i][ks]);
#pragma unroll
      for (int j = 0; j < 4; ++j) bfr[j] = *(const bf16x8*)(lds + bo + bro[j][ks]);
#pragma unroll
      for (int i = 0; i < 4; ++i)
#pragma unroll
        for (int j = 0; j < 4; ++j)
          acc[i][j] = __builtin_amdgcn_mfma_f32_16x16x32_bf16(af[i], bfr[j], acc[i][j], 0, 0, 0);
    }
  };

  // prologue: fill both buffers (16 loads in flight)
  stage_fn(0, 0);
  stage_fn(1, 32768);

#pragma unroll 2
  for (int st = 0; st < 36; ++st) {
    const int bo = (st & 1) << 15;
    // wait for stage st's 8 loads; keep stage st+1's 8 in flight (never drain to 0 mid-loop)
    if (st == 35) {
      asm volatile("s_waitcnt vmcnt(0)" ::: "memory");
    } else {
      asm volatile("s_waitcnt vmcnt(8)" ::: "memory");
    }
    __builtin_amdgcn_s_barrier();          // buf[st&1] ready for all waves
    __builtin_amdgcn_sched_barrier(0);     // keep ds_reads below the barrier
    __builtin_amdgcn_s_setprio(1);
    compute_fn(bo);
    __builtin_amdgcn_s_setprio(0);
    __builtin_amdgcn_s_barrier();          // all waves done reading buf[st&1]
    __builtin_amdgcn_sched_barrier(0);     // keep prefetch below the barrier
    if (st < 34) stage_fn(st + 2, bo);     // overwrite just-freed buffer
  }

  // epilogue: D[m][n]: lane reg r -> m = quad*4+r, n = col  (m89/m91-verified layout)
  const float nw0 = nwt[0];
  const int p0 = bx * 128;
  float nz[4];
#pragma unroll
  for (int j = 0; j < 4; ++j)
    nz[j] = noise[(b << 12) + p0 + nwl + j * 16 + col] * nw0;
#pragma unroll
  for (int i = 0; i < 4; ++i) {
    int mloc = mw + i * 16 + quad * 4;
#pragma unroll
    for (int j = 0; j < 4; ++j) {
      int p = p0 + nwl + j * 16 + col;
      f32x4 v = acc[i][j];
#pragma unroll
      for (int r = 0; r < 4; ++r) {
        int coutg = cout0 + mloc + r;
        float val = v[r] + nz[j] + bias[coutg];
        val = (val > 0.f ? val : 0.2f * val) * 1.4142135623730951f;
        out[(((size_t)(b * 256 + coutg)) << 12) + p] = val;
      }
    }
  }
}

extern "C" void kernel_launch(void* const* d_in, const int* in_sizes, int n_in,
                              void* d_out, int out_size, void* d_ws, size_t ws_size,
                              hipStream_t stream) {
  const float* x        = (const float*)d_in[0];
  const float* style    = (const float*)d_in[1];
  const float* noise    = (const float*)d_in[2];
  const float* weight   = (const float*)d_in[3];
  const float* style_w  = (const float*)d_in[4];
  const float* style_b  = (const float*)d_in[5];
  const float* bias     = (const float*)d_in[6];
  const float* noise_w  = (const float*)d_in[7];
  float* out = (float*)d_out;

  char* ws = (char*)d_ws;
  float* smod = (float*)ws;                                    // 16 KB
  __hip_bfloat16* wmod = (__hip_bfloat16*)(ws + 16384);        // 18.87 MB
  __hip_bfloat16* xt = (__hip_bfloat16*)(ws + 16384 + 18874368);  // 35.68 MB

  style_kernel<<<16, 256, 0, stream>>>(style, style_w, style_b, smod);
  modw_kernel<<<dim3(256, 16), 256, 0, stream>>>(weight, smod, wmod);
  border_kernel<<<dim3(260, 16), 256, 0, stream>>>(xt);
  transpose_kernel<<<dim3(64, 16), 256, 0, stream>>>(x, xt);
  conv_kernel<<<dim3(32, 2, 16), 256, 0, stream>>>(wmod, xt, noise, bias, noise_w, out);
}